// Round 7
// baseline (336.042 us; speedup 1.0000x reference)
//
#include <hip/hip_runtime.h>
#include <stdint.h>
#include <stddef.h>

// Problem constants
#define IN_F   4096
#define OUT_F  14336
#define TOK    32

// Tiling: one block = 16 adjacent o-rows x FULL K  (contiguous 256 KB weight span)
#define OTILE  16
#define KWAVE  (IN_F / 4)         // 1024 i per wave (4 waves split K)
#define KBW    (KWAVE / 32)       // 32 MFMA K-blocks per wave

typedef __attribute__((ext_vector_type(8))) short bf16x8;
typedef __attribute__((ext_vector_type(4))) float f32x4;

// prep: xs = x*scales as bf16 in MFMA A-operand fragment order:
//   element (t,i): kb=i>>5, mt=t>>4, lane=((i>>3)&3)*16 + (t&15), j=i&7
//   int4 slot index = (kb*2+mt)*64 + lane   (j packed inside the int4)
// 16384 slots, one thread each. (No d_out zeroing — qgemm stores directly.)
__global__ __launch_bounds__(256) void prep_kernel(
    const float* __restrict__ x, const float* __restrict__ scales,
    int4* __restrict__ xfrag)
{
    const int f = blockIdx.x * 256 + threadIdx.x;   // grid 64 -> 0..16383
    const int t  = f >> 9;                          // 0..31
    const int i8 = f & 511;                         // i = 8*i8 .. 8*i8+7
    const int kb = i8 >> 2;                         // i>>5
    const int kg = i8 & 3;                          // (i>>3)&3
    const float4* xp = (const float4*)(x + (size_t)t * IN_F + i8 * 8);
    const float4* sp = (const float4*)(scales + i8 * 8);
    float4 x0 = xp[0], x1 = xp[1];
    float4 s0 = sp[0], s1 = sp[1];
    float v[8] = { x0.x*s0.x, x0.y*s0.y, x0.z*s0.z, x0.w*s0.w,
                   x1.x*s1.x, x1.y*s1.y, x1.z*s1.z, x1.w*s1.w };
    uint32_t h[8];
#pragma unroll
    for (int j = 0; j < 8; ++j) {                   // fp32 -> bf16 RNE
        uint32_t b = __float_as_uint(v[j]);
        b += 0x7fffu + ((b >> 16) & 1u);
        h[j] = b >> 16;
    }
    int4 d;
    d.x = (int)(h[0] | (h[1] << 16));
    d.y = (int)(h[2] | (h[3] << 16));
    d.z = (int)(h[4] | (h[5] << 16));
    d.w = (int)(h[6] | (h[7] << 16));
    xfrag[((kb * 2 + (t >> 4)) * 64) + kg * 16 + (t & 15)] = d;
}

// Main kernel: 896 blocks (all co-resident at 4/CU), block owns out[32, 16o].
// Weight footprint per block = rows [o0,o0+16) x full K = CONTIGUOUS 256 KB,
// streamed front-to-back by 4 waves on disjoint K-quarters -> DRAM sees ~3.5k
// forward sequential streams, no 128B-scatter. No atomics: 4-way cross-wave
// K-reduction through LDS, direct stores. A-frags reloaded per-kb from xfrag
// (256 KB, L2-resident per XCD). int->bf16 cvt exact (|w|<=127).
__global__ __launch_bounds__(256, 4) void qgemm_kernel(
    const int* __restrict__ wgt, const int4* __restrict__ xfrag,
    float* __restrict__ out)
{
    __shared__ float lred[4][8][64];                // 8 KB
    const int lane = threadIdx.x & 63;
    const int wv   = threadIdx.x >> 6;              // 0..3 = K-quarter
    const int lx   = lane & 15;                     // B col = o offset
    const int quad = lane >> 4;                     // B k-group
    const int o0   = blockIdx.x * OTILE;

    // my B row pointer: row o0+lx, k base wv*1024 + quad*8
    const int* wp = wgt + (size_t)(o0 + lx) * IN_F + wv * KWAVE + quad * 8;
    const int4* ap = xfrag + ((size_t)wv * KBW) * 2 * 64 + lane;

    f32x4 acc[2] = { {0.f,0.f,0.f,0.f}, {0.f,0.f,0.f,0.f} };

#pragma unroll 8
    for (int kb = 0; kb < KBW; ++kb) {
        // A fragments for this K-block (L2-hot, coalesced 1 KB per wave-load)
        int4 av0 = ap[(kb * 2 + 0) * 64];
        int4 av1 = ap[(kb * 2 + 1) * 64];
        // W: 8 consecutive int32 of my row at k = wv*1024 + kb*32 + quad*8
        const int4 w0 = *(const int4*)(wp + kb * 32);
        const int4 w1 = *(const int4*)(wp + kb * 32 + 4);
        bf16x8 b;
        b[0] = (short)(__float_as_uint((float)w0.x) >> 16);
        b[1] = (short)(__float_as_uint((float)w0.y) >> 16);
        b[2] = (short)(__float_as_uint((float)w0.z) >> 16);
        b[3] = (short)(__float_as_uint((float)w0.w) >> 16);
        b[4] = (short)(__float_as_uint((float)w1.x) >> 16);
        b[5] = (short)(__float_as_uint((float)w1.y) >> 16);
        b[6] = (short)(__float_as_uint((float)w1.z) >> 16);
        b[7] = (short)(__float_as_uint((float)w1.w) >> 16);
        bf16x8 a0, a1;
        __builtin_memcpy(&a0, &av0, 16);
        __builtin_memcpy(&a1, &av1, 16);
        acc[0] = __builtin_amdgcn_mfma_f32_16x16x32_bf16(a0, b, acc[0], 0, 0, 0);
        acc[1] = __builtin_amdgcn_mfma_f32_16x16x32_bf16(a1, b, acc[1], 0, 0, 0);
    }

    // Cross-wave K-reduction: lred[wv][s][lane], conflict-free both directions.
#pragma unroll
    for (int s = 0; s < 8; ++s)
        lred[wv][s][lane] = acc[s >> 2][s & 3];
    __syncthreads();

    if (wv == 0) {
        // C/D layout: D[row=quad*4+reg][col=lx]; s = mt*4+reg,
        // t = mt*16 + quad*4 + reg, o = o0 + lx.
#pragma unroll
        for (int s = 0; s < 8; ++s) {
            const float v = lred[0][s][lane] + lred[1][s][lane]
                          + lred[2][s][lane] + lred[3][s][lane];
            const int t = (s >> 2) * 16 + quad * 4 + (s & 3);
            out[(size_t)t * OUT_F + o0 + lx] = v;
        }
    }
}

extern "C" void kernel_launch(void* const* d_in, const int* in_sizes, int n_in,
                              void* d_out, int out_size, void* d_ws, size_t ws_size,
                              hipStream_t stream)
{
    const float* x      = (const float*)d_in[0];   // [32, 4096] fp32
    const int*   wgt    = (const int*)d_in[1];     // [14336, 4096] int32 (int8 vals)
    const float* scales = (const float*)d_in[2];   // [4096] fp32
    float* out = (float*)d_out;                    // [32, 14336] fp32
    int4*  xfrag = (int4*)d_ws;                    // 256 KB scratch (A-frags)

    prep_kernel<<<dim3((TOK * IN_F / 8) / 256), 256, 0, stream>>>(x, scales, xfrag);

    qgemm_kernel<<<dim3(OUT_F / OTILE), 256, 0, stream>>>(wgt, xfrag, out);
}

// Round 9
// 321.270 us; speedup vs baseline: 1.0460x; 1.0460x over previous
//
#include <hip/hip_runtime.h>
#include <stdint.h>
#include <stddef.h>

// Problem constants
#define IN_F   4096
#define OUT_F  14336
#define TOK    32

// Tiling: block = 16 adjacent o-rows x full K; K staged in chunks of 512 i.
#define OTILE  16
#define CHUNK  512                // i per staged chunk (2 KB per row)
#define NCH    (IN_F / CHUNK)     // 8 chunk iterations
#define KBC    (CHUNK / 32)       // 16 MFMA K-blocks per chunk
#define KBW    (KBC / 4)          // 4 K-blocks per wave per chunk
#define ROWPAD 516                // ints per LDS row (512 + 4 pad -> bank-uniform)

typedef const __attribute__((address_space(1))) void* gas_ptr;
typedef __attribute__((address_space(3))) void* las_ptr;
typedef __attribute__((ext_vector_type(8))) short bf16x8;
typedef __attribute__((ext_vector_type(4))) float f32x4;

// prep: xs = x*scales as bf16 in MFMA A-operand fragment order:
//   element (t,i): kb=i>>5, mt=t>>4, lane=((i>>3)&3)*16 + (t&15), j=i&7
//   int4 slot index = (kb*2+mt)*64 + lane   (j packed inside the int4)
__global__ __launch_bounds__(256) void prep_kernel(
    const float* __restrict__ x, const float* __restrict__ scales,
    int4* __restrict__ xfrag)
{
    const int f = blockIdx.x * 256 + threadIdx.x;   // grid 64 -> 0..16383
    const int t  = f >> 9;                          // 0..31
    const int i8 = f & 511;                         // i = 8*i8 .. 8*i8+7
    const int kb = i8 >> 2;
    const int kg = i8 & 3;
    const float4* xp = (const float4*)(x + (size_t)t * IN_F + i8 * 8);
    const float4* sp = (const float4*)(scales + i8 * 8);
    float4 x0 = xp[0], x1 = xp[1];
    float4 s0 = sp[0], s1 = sp[1];
    float v[8] = { x0.x*s0.x, x0.y*s0.y, x0.z*s0.z, x0.w*s0.w,
                   x1.x*s1.x, x1.y*s1.y, x1.z*s1.z, x1.w*s1.w };
    uint32_t h[8];
#pragma unroll
    for (int j = 0; j < 8; ++j) {                   // fp32 -> bf16 RNE
        uint32_t b = __float_as_uint(v[j]);
        b += 0x7fffu + ((b >> 16) & 1u);
        h[j] = b >> 16;
    }
    int4 d;
    d.x = (int)(h[0] | (h[1] << 16));
    d.y = (int)(h[2] | (h[3] << 16));
    d.z = (int)(h[4] | (h[5] << 16));
    d.w = (int)(h[6] | (h[7] << 16));
    xfrag[((kb * 2 + (t >> 4)) * 64) + kg * 16 + (t & 15)] = d;
}

// Main kernel: weight staging instrs are each ONE CONTIGUOUS 1 KB burst:
// global source = per-lane address (base + lane*16B  <-- R8's bug: this was
// wave-uniform, every lane fetched the same 16 B), LDS dest = wave-uniform
// base (+lane*16B added by HW). 2 KB per-row granule per chunk, ~8K
// device-wide streams — the fill-like pattern HBM runs at 6.7 TB/s.
// MFMA reads the tile back from LDS (row stride 516 ints -> b128 readback at
// the 8-touch/bank floor). 4 waves split chunk-K 4-ways; cross-wave reduce
// via LDS; direct stores, no atomics.
__global__ __launch_bounds__(256, 2) void qgemm_kernel(
    const int* __restrict__ wgt, const int4* __restrict__ xfrag,
    float* __restrict__ out)
{
    __shared__ int   wbuf[2][OTILE * ROWPAD];       // 2 x 33024 B
    __shared__ float lred[4][8][64];                // 8 KB
    const int lane = threadIdx.x & 63;
    const int wv   = threadIdx.x >> 6;              // 0..3
    const int wvu  = __builtin_amdgcn_readfirstlane(wv);
    const int lx   = lane & 15;                     // B col = o offset
    const int quad = lane >> 4;                     // B k-group
    const int o0   = blockIdx.x * OTILE;

    // Stage chunk c: wave wv stages rows [4wv,4wv+4), 2 KB each = 2 x 1 KB
    // contiguous instrs. Source is PER-LANE (base + lane*16B); LDS dest is
    // wave-uniform row base (HW adds lane*16B). Row r at byte r*2064.
    auto stage = [&](int buf, int c) {
#pragma unroll
        for (int rr = 0; rr < 4; ++rr) {
            const int r = wvu * 4 + rr;
            const int* src = wgt + (size_t)(o0 + r) * IN_F + c * CHUNK
                                 + lane * 4;        // lane*16 B within the burst
            int* dst = &wbuf[buf][r * ROWPAD];
            __builtin_amdgcn_global_load_lds((gas_ptr)src, (las_ptr)dst, 16, 0, 0);
            __builtin_amdgcn_global_load_lds((gas_ptr)(src + 256),
                                             (las_ptr)(dst + 256), 16, 0, 0);
        }
    };

    f32x4 acc[2] = { {0.f,0.f,0.f,0.f}, {0.f,0.f,0.f,0.f} };

    stage(0, 0);
    __syncthreads();

    int cur = 0;
    for (int c = 0; c < NCH; ++c) {
        if (c + 1 < NCH) stage(cur ^ 1, c + 1);     // prefetch next chunk

        // my B lane: row lx, k-offset quad*8 within each K-block
        const int* lb = &wbuf[cur][lx * ROWPAD + quad * 8];
#pragma unroll
        for (int q = 0; q < KBW; ++q) {
            const int l   = wvu * KBW + q;          // local K-block 0..15
            const int kbg = c * KBC + l;            // global K-block
            int4 av0 = xfrag[((size_t)kbg * 2 + 0) * 64 + lane];
            int4 av1 = xfrag[((size_t)kbg * 2 + 1) * 64 + lane];
            const int4 w0 = *(const int4*)(lb + l * 32);
            const int4 w1 = *(const int4*)(lb + l * 32 + 4);
            // int -> bf16 exact (|w|<=127 fits bf16's 8-bit mantissa)
            bf16x8 b;
            b[0] = (short)(__float_as_uint((float)w0.x) >> 16);
            b[1] = (short)(__float_as_uint((float)w0.y) >> 16);
            b[2] = (short)(__float_as_uint((float)w0.z) >> 16);
            b[3] = (short)(__float_as_uint((float)w0.w) >> 16);
            b[4] = (short)(__float_as_uint((float)w1.x) >> 16);
            b[5] = (short)(__float_as_uint((float)w1.y) >> 16);
            b[6] = (short)(__float_as_uint((float)w1.z) >> 16);
            b[7] = (short)(__float_as_uint((float)w1.w) >> 16);
            bf16x8 a0, a1;
            __builtin_memcpy(&a0, &av0, 16);
            __builtin_memcpy(&a1, &av1, 16);
            acc[0] = __builtin_amdgcn_mfma_f32_16x16x32_bf16(a0, b, acc[0], 0, 0, 0);
            acc[1] = __builtin_amdgcn_mfma_f32_16x16x32_bf16(a1, b, acc[1], 0, 0, 0);
        }
        __syncthreads();   // staging drain; next iter reads cur^1
        cur ^= 1;
    }

    // Cross-wave K-reduction: lred[wv][s][lane], conflict-free both directions.
#pragma unroll
    for (int s = 0; s < 8; ++s)
        lred[wv][s][lane] = acc[s >> 2][s & 3];
    __syncthreads();

    if (wv == 0) {
        // C/D layout: D[row=quad*4+reg][col=lx]; t = mt*16 + quad*4 + reg.
#pragma unroll
        for (int s = 0; s < 8; ++s) {
            const float v = lred[0][s][lane] + lred[1][s][lane]
                          + lred[2][s][lane] + lred[3][s][lane];
            const int t = (s >> 2) * 16 + quad * 4 + (s & 3);
            out[(size_t)t * OUT_F + o0 + lx] = v;
        }
    }
}

extern "C" void kernel_launch(void* const* d_in, const int* in_sizes, int n_in,
                              void* d_out, int out_size, void* d_ws, size_t ws_size,
                              hipStream_t stream)
{
    const float* x      = (const float*)d_in[0];   // [32, 4096] fp32
    const int*   wgt    = (const int*)d_in[1];     // [14336, 4096] int32 (int8 vals)
    const float* scales = (const float*)d_in[2];   // [4096] fp32
    float* out = (float*)d_out;                    // [32, 14336] fp32
    int4*  xfrag = (int4*)d_ws;                    // 256 KB scratch (A-frags)

    prep_kernel<<<dim3((TOK * IN_F / 8) / 256), 256, 0, stream>>>(x, scales, xfrag);

    qgemm_kernel<<<dim3(OUT_F / OTILE), 256, 0, stream>>>(wgt, xfrag, out);
}